// Round 6
// baseline (690.802 us; speedup 1.0000x reference)
//
#include <hip/hip_runtime.h>
#include <math.h>

#define NN 50000
#define NE 800000
#define DF 128
#define GEMM_ROWS 64
#define SCAN_M (2 * NN)
#define SCAN_BLKS ((SCAN_M + 1023) / 1024)
#define NPART 8
#define PART_SZ (NN / NPART)        // 6250, exact
#define STG_CAP 108544              // 100000 expected + huge slack
#define BIN_BLOCKS 512              // first half graph 1, second half graph 2
#define BUCK_CAP 512
#define PP_BLOCKS 512               // histp grid: 8 parts x 2 graphs x 32 blocks
#define CHUNKS 16                   // node-chunks per part for place_sorted
#define CH_W 391                    // ceil(PART_SZ / CHUNKS)
#define SORT_CAP 7680               // chunk mean 6256 edges, +18 sigma

// ---------------- phase B: bin edges by dst-part into staging ----------------
// Ballot-based ranking: no LDS atomics, no per-edge atomics.
__global__ __launch_bounds__(256) void bin_kernel(const int* __restrict__ src1, const int* __restrict__ dst1,
                                                  const int* __restrict__ src2, const int* __restrict__ dst2,
                                                  int2* __restrict__ stg, int* __restrict__ stgcnt) {
    __shared__ int2 buck[NPART][BUCK_CAP];   // 32 KB
    __shared__ int bcnt[NPART];
    __shared__ int wbase[4][NPART];
    __shared__ int gbase[NPART];
    const int t = threadIdx.x, lane = t & 63, w = t >> 6;
    const int g = (blockIdx.x >= BIN_BLOCKS / 2) ? 1 : 0;
    const int bid = blockIdx.x - g * (BIN_BLOCKS / 2);
    const int nb = BIN_BLOCKS / 2;
    const int* __restrict__ srcv = g ? src2 : src1;
    const int* __restrict__ dstv = g ? dst2 : dst1;
    int2* __restrict__ stg_g = stg + (size_t)g * NPART * STG_CAP;
    int* __restrict__ cnt_g = stgcnt + g * NPART;
    if (t < NPART) bcnt[t] = 0;
    __syncthreads();
    for (int base = bid * 256; base < NE; base += nb * 256) {  // per-block uniform trip count
        const int e = base + t;
        const bool v = (e < NE);
        int d = 0, s = 0, p = -1;
        if (v) { d = dstv[e]; s = srcv[e]; p = d / PART_SZ; }
        int rank = 0;
        const unsigned long long lt = (1ull << lane) - 1ull;
        int wc[NPART];
        #pragma unroll
        for (int q = 0; q < NPART; q++) {
            unsigned long long m = __ballot(p == q);
            wc[q] = (int)__popcll(m);
            if (p == q) rank = (int)__popcll(m & lt);
        }
        if (lane < NPART) wbase[w][lane] = wc[lane];
        __syncthreads();                                  // (1)
        if (t < NPART) {  // cross-wave exclusive prefix for part t
            int b = bcnt[t];
            int c0 = wbase[0][t], c1 = wbase[1][t], c2 = wbase[2][t], c3 = wbase[3][t];
            wbase[0][t] = b;
            wbase[1][t] = b + c0;
            wbase[2][t] = b + c0 + c1;
            wbase[3][t] = b + c0 + c1 + c2;
            bcnt[t] = b + c0 + c1 + c2 + c3;              // <= 255 + 256 < BUCK_CAP
        }
        __syncthreads();                                  // (2)
        if (v) buck[p][wbase[w][p] + rank] = make_int2(s, d);
        __syncthreads();                                  // (3)
        const bool last = (base + nb * 256) >= NE;        // block-uniform
        if (t < NPART) {
            int c = bcnt[t];
            gbase[t] = (c >= 256 || (last && c > 0)) ? atomicAdd(&cnt_g[t], c) : -1;
        }
        __syncthreads();                                  // (4)
        #pragma unroll
        for (int q = 0; q < NPART; q++) {
            int gb = gbase[q];
            if (gb >= 0) {
                int c = bcnt[q];
                for (int i = t; i < c; i += 256)
                    stg_g[(size_t)q * STG_CAP + gb + i] = buck[q][i];
            }
        }
        __syncthreads();                                  // (5) protect buck before next fill
        if (t < NPART && gbase[t] >= 0) bcnt[t] = 0;      // next read is after next iter's (1)
    }
}

// ---------------- phase C: histogram from staging (L2-local atomics per part) ----------------
__global__ __launch_bounds__(256) void histp_kernel(const int2* __restrict__ stg, const int* __restrict__ stgcnt,
                                                    int* __restrict__ cnt /* cnt1|cnt2 */) {
    const int p = blockIdx.x % NPART;     // XCD round-robin
    const int q = blockIdx.x / NPART;     // 0..63
    const int g = (q >= 32) ? 1 : 0;
    const int qq = q & 31;
    const int m = stgcnt[g * NPART + p];
    const int2* __restrict__ seg = stg + ((size_t)g * NPART + p) * STG_CAP;
    int* __restrict__ cnt_g = cnt + g * NN;
    for (int i = qq * 256 + threadIdx.x; i < m; i += 32 * 256)
        atomicAdd(&cnt_g[seg[i].y], 1);
}

// ---------------- scan phase A: per-block exclusive scan + block sums ----------------
__global__ __launch_bounds__(1024) void scanA_kernel(const int* __restrict__ cnt, int* __restrict__ exloc,
                                                     int* __restrict__ bsum) {
    __shared__ int wsum[16];
    const int t = threadIdx.x, lane = t & 63, wid = t >> 6;
    int i = blockIdx.x * 1024 + t;
    int v = (i < SCAN_M) ? cnt[i] : 0;
    int x = v;
    #pragma unroll
    for (int off = 1; off < 64; off <<= 1) { int y = __shfl_up(x, off); if (lane >= off) x += y; }
    if (lane == 63) wsum[wid] = x;
    __syncthreads();
    if (t < 16) {
        int w = wsum[t];
        #pragma unroll
        for (int off = 1; off < 16; off <<= 1) { int y = __shfl_up(w, off); if (t >= off) w += y; }
        wsum[t] = w;
    }
    __syncthreads();
    int excl = (wid ? wsum[wid - 1] : 0) + (x - v);
    if (i < SCAN_M) exloc[i] = excl;
    if (t == 0) bsum[blockIdx.x] = wsum[15];
}

// ---------------- scan phase B: scan the block sums (tiny) ----------------
__global__ __launch_bounds__(128) void scanB_kernel(const int* __restrict__ bsum, int* __restrict__ boff,
                                                    int* __restrict__ rp1, int* __restrict__ rp2) {
    __shared__ int wtot[2];
    const int t = threadIdx.x, lane = t & 63, wid = t >> 6;
    int v = (t < SCAN_BLKS) ? bsum[t] : 0;
    int x = v;
    #pragma unroll
    for (int off = 1; off < 64; off <<= 1) { int y = __shfl_up(x, off); if (lane >= off) x += y; }
    if (lane == 63) wtot[wid] = x;
    __syncthreads();
    int excl = ((wid == 1) ? wtot[0] : 0) + (x - v);
    if (t < SCAN_BLKS) boff[t] = excl;
    if (t == 0) { rp1[NN] = NE; rp2[NN] = NE; }  // graph-1 degree total is exactly NE
}

// ---------------- scan phase C: finalize rp + dinv ----------------
__global__ __launch_bounds__(1024) void scanC_kernel(const int* __restrict__ cnt, const int* __restrict__ exloc,
                                                     const int* __restrict__ boff,
                                                     int* __restrict__ rp1, float* __restrict__ dinv1,
                                                     int* __restrict__ rp2, float* __restrict__ dinv2) {
    int i = blockIdx.x * 1024 + threadIdx.x;
    if (i >= SCAN_M) return;
    int ex = exloc[i] + boff[blockIdx.x];
    float dv = rsqrtf((float)cnt[i] + 1.0f);  // +1 self loop
    if (i < NN) { rp1[i] = ex; dinv1[i] = dv; }
    else { int j = i - NN; rp2[j] = ex - NE; dinv2[j] = dv; }
}

// ---------------- phase D: LDS-sorted placement, fully coalesced pk writes ----------------
// Scattered sub-line global stores cost ~a full 64B line each (measured r2/3/5:
// 6.4x amp for 8B stores regardless of window size) -> sort each chunk's segment
// in LDS and stream it out coalesced. blockIdx%8 = part keeps the part's staging
// segment L2-resident across its 16 chunk-blocks (round-robin XCD dispatch).
__global__ __launch_bounds__(256) void place_sorted_kernel(const int2* __restrict__ stg, const int* __restrict__ stgcnt,
                                                           const int* __restrict__ rp1, const int* __restrict__ rp2,
                                                           const float* __restrict__ dinv1, const float* __restrict__ dinv2,
                                                           int2* __restrict__ pk1, int2* __restrict__ pk2) {
    __shared__ int2 sorted[SORT_CAP];   // 60 KB
    __shared__ int fill[CH_W];
    __shared__ int rps[CH_W + 1];
    const int t = threadIdx.x;
    const int p = blockIdx.x & 7;            // part -> XCD under round-robin
    const int rest = blockIdx.x >> 3;
    const int c = rest & (CHUNKS - 1);
    const int g = rest >> 4;
    const int m = stgcnt[g * NPART + p];
    const int2* __restrict__ seg = stg + ((size_t)g * NPART + p) * STG_CAP;
    const int* __restrict__ rp = g ? rp2 : rp1;
    const float* __restrict__ dinv = g ? dinv2 : dinv1;
    int2* __restrict__ pk = g ? pk2 : pk1;
    const int lo = p * PART_SZ + c * CH_W;
    int hi = lo + CH_W;
    const int pend = (p + 1) * PART_SZ;
    if (hi > pend) hi = pend;                // last chunk: 385 nodes
    const int nw = hi - lo;
    for (int i = t; i < nw; i += 256) { fill[i] = 0; rps[i] = rp[lo + i]; }
    if (t == 0) rps[nw] = rp[hi];
    __syncthreads();
    const int segbase = rps[0];
    const int total = rps[nw] - segbase;
    for (int i = t; i < m; i += 256) {       // L2-served after first chunk-block touches it
        int2 e = seg[i];
        int dl = e.y - lo;
        if ((unsigned)dl < (unsigned)nw) {
            int lp = rps[dl] - segbase + atomicAdd(&fill[dl], 1);
            if (lp < SORT_CAP)               // statistically never exceeded
                sorted[lp] = make_int2(e.x, __float_as_int(dinv[e.x]));
        }
    }
    __syncthreads();
    for (int i = t; i < total; i += 256)     // coalesced 8B stores
        pk[segbase + i] = sorted[i];
}

// ---------------- H = X @ W ----------------
__global__ __launch_bounds__(256) void gemm128_kernel(const float* __restrict__ X, const float* __restrict__ W,
                                                      float* __restrict__ H, int n) {
    __shared__ __align__(16) float Xs[GEMM_ROWS * DF];  // 32 KB
    const int t = threadIdx.x;
    const int row_base = blockIdx.x * GEMM_ROWS;
    {
        const float4* X4 = (const float4*)(X + (size_t)row_base * DF);
        float4* Xs4 = (float4*)Xs;
        #pragma unroll
        for (int it = 0; it < (GEMM_ROWS * DF / 4) / 256; it++) {
            int idx = t + 256 * it;
            int r = idx >> 5;
            float4 v = make_float4(0.f, 0.f, 0.f, 0.f);
            if (row_base + r < n) v = X4[idx];
            Xs4[idx] = v;
        }
    }
    __syncthreads();
    const int cg = t & 31;
    const int rg = t >> 5;
    const int c0 = cg * 4;
    const int lr0 = rg * 8;
    float4 acc[8];
    #pragma unroll
    for (int r = 0; r < 8; r++) acc[r] = make_float4(0.f, 0.f, 0.f, 0.f);
    #pragma unroll 4
    for (int k0 = 0; k0 < DF; k0 += 4) {
        float4 wv0 = *(const float4*)(W + (size_t)(k0 + 0) * DF + c0);
        float4 wv1 = *(const float4*)(W + (size_t)(k0 + 1) * DF + c0);
        float4 wv2 = *(const float4*)(W + (size_t)(k0 + 2) * DF + c0);
        float4 wv3 = *(const float4*)(W + (size_t)(k0 + 3) * DF + c0);
        #pragma unroll
        for (int r = 0; r < 8; r++) {
            float4 xv = *(const float4*)(Xs + (lr0 + r) * DF + k0);
            acc[r].x = fmaf(xv.x, wv0.x, acc[r].x); acc[r].y = fmaf(xv.x, wv0.y, acc[r].y);
            acc[r].z = fmaf(xv.x, wv0.z, acc[r].z); acc[r].w = fmaf(xv.x, wv0.w, acc[r].w);
            acc[r].x = fmaf(xv.y, wv1.x, acc[r].x); acc[r].y = fmaf(xv.y, wv1.y, acc[r].y);
            acc[r].z = fmaf(xv.y, wv1.z, acc[r].z); acc[r].w = fmaf(xv.y, wv1.w, acc[r].w);
            acc[r].x = fmaf(xv.z, wv2.x, acc[r].x); acc[r].y = fmaf(xv.z, wv2.y, acc[r].y);
            acc[r].z = fmaf(xv.z, wv2.z, acc[r].z); acc[r].w = fmaf(xv.z, wv2.w, acc[r].w);
            acc[r].x = fmaf(xv.w, wv3.x, acc[r].x); acc[r].y = fmaf(xv.w, wv3.y, acc[r].y);
            acc[r].z = fmaf(xv.w, wv3.z, acc[r].z); acc[r].w = fmaf(xv.w, wv3.w, acc[r].w);
        }
    }
    #pragma unroll
    for (int r = 0; r < 8; r++) {
        int row = row_base + lr0 + r;
        if (row < n) *(float4*)(H + (size_t)row * DF + c0) = acc[r];
    }
}

// ---------------- aggregation: one wave per dst node (round-3 measured-good version) ----------------
__global__ __launch_bounds__(256) void agg_kernel(const float* __restrict__ H, const int* __restrict__ rp,
                                                  const int2* __restrict__ pk,
                                                  const float* __restrict__ dinv, const float* __restrict__ bias,
                                                  float* __restrict__ out, int n, int act) {
    const int lane = threadIdx.x & 63;
    const int sub = lane & 31;
    const int half = lane >> 5;
    const int i = blockIdx.x * 4 + (threadIdx.x >> 6);
    if (i >= n) return;
    const int start = rp[i];
    const int end = rp[i + 1];
    float ax = 0.f, ay = 0.f, az = 0.f, aw = 0.f;
    const float* __restrict__ Hc = H + 4 * sub;
    for (int base = start; base < end; base += 64) {
        int cnt = end - base;
        if (cnt > 64) cnt = 64;
        int msrc = 0;
        float mdv = 0.f;
        if (lane < cnt) {  // coalesced 8B batch load of packed (src, coef)
            int2 pv = pk[base + lane];
            msrc = pv.x;
            mdv = __int_as_float(pv.y);
        }
        for (int j = 0; j < cnt; j += 8) {  // 8 edges per iter; 4 float4 gathers in flight
            int e0 = j + half;              // halves take even/odd edges; pads have mdv==0
            int s0 = __shfl(msrc, e0),     s1 = __shfl(msrc, e0 + 2);
            int s2 = __shfl(msrc, e0 + 4), s3 = __shfl(msrc, e0 + 6);
            float d0 = __shfl(mdv, e0),     d1 = __shfl(mdv, e0 + 2);
            float d2 = __shfl(mdv, e0 + 4), d3 = __shfl(mdv, e0 + 6);
            float4 h0 = *(const float4*)(Hc + (size_t)s0 * DF);
            float4 h1 = *(const float4*)(Hc + (size_t)s1 * DF);
            float4 h2 = *(const float4*)(Hc + (size_t)s2 * DF);
            float4 h3 = *(const float4*)(Hc + (size_t)s3 * DF);
            ax = fmaf(d0, h0.x, ax); ay = fmaf(d0, h0.y, ay); az = fmaf(d0, h0.z, az); aw = fmaf(d0, h0.w, aw);
            ax = fmaf(d1, h1.x, ax); ay = fmaf(d1, h1.y, ay); az = fmaf(d1, h1.z, az); aw = fmaf(d1, h1.w, aw);
            ax = fmaf(d2, h2.x, ax); ay = fmaf(d2, h2.y, ay); az = fmaf(d2, h2.z, az); aw = fmaf(d2, h2.w, aw);
            ax = fmaf(d3, h3.x, ax); ay = fmaf(d3, h3.y, ay); az = fmaf(d3, h3.z, az); aw = fmaf(d3, h3.w, aw);
        }
    }
    // fold halves: lanes 0-31 += lanes 32-63
    ax += __shfl_down(ax, 32); ay += __shfl_down(ay, 32);
    az += __shfl_down(az, 32); aw += __shfl_down(aw, 32);
    if (half == 0) {
        float di = dinv[i];
        float dii = di * di;
        float4 hv = *(const float4*)(H + (size_t)i * DF + 4 * sub);
        float4 bv = *(const float4*)(bias + 4 * sub);
        float ox = fmaf(di, ax, fmaf(dii, hv.x, bv.x));
        float oy = fmaf(di, ay, fmaf(dii, hv.y, bv.y));
        float oz = fmaf(di, az, fmaf(dii, hv.z, bv.z));
        float ow = fmaf(di, aw, fmaf(dii, hv.w, bv.w));
        if (act == 0) {  // ELU
            ox = ox > 0.f ? ox : expm1f(ox);
            oy = oy > 0.f ? oy : expm1f(oy);
            oz = oz > 0.f ? oz : expm1f(oz);
            ow = ow > 0.f ? ow : expm1f(ow);
        } else {  // ReLU
            ox = fmaxf(ox, 0.f); oy = fmaxf(oy, 0.f);
            oz = fmaxf(oz, 0.f); ow = fmaxf(ow, 0.f);
        }
        float4 ov; ov.x = ox; ov.y = oy; ov.z = oz; ov.w = ow;
        *(float4*)(out + (size_t)i * DF + 4 * sub) = ov;
    }
}

extern "C" void kernel_launch(void* const* d_in, const int* in_sizes, int n_in,
                              void* d_out, int out_size, void* d_ws, size_t ws_size,
                              hipStream_t stream) {
    const float* x  = (const float*)d_in[0];
    const float* W1 = (const float*)d_in[1];
    const float* b1 = (const float*)d_in[2];
    const float* W2 = (const float*)d_in[3];
    const float* b2 = (const float*)d_in[4];
    const float* W3 = (const float*)d_in[5];
    const float* b3 = (const float*)d_in[6];
    const float* W4 = (const float*)d_in[7];
    const float* b4 = (const float*)d_in[8];
    const int* ei1 = (const int*)d_in[9];
    const int* ei2 = (const int*)d_in[10];
    const int *src1 = ei1, *dst1 = ei1 + NE;
    const int *src2 = ei2, *dst2 = ei2 + NE;

    // ---- workspace carve-out (512B aligned), ~80 MB ----
    char* ws = (char*)d_ws;
    size_t off = 0;
    auto carve = [&](size_t bytes) -> void* {
        void* p = (void*)(ws + off);
        off += (bytes + 511) & ~(size_t)511;
        return p;
    };
    int* cnt = (int*)carve((size_t)SCAN_M * 4);       // cnt1|cnt2 contiguous
    int* stgcnt = (int*)carve((size_t)16 * 4);        // right after cnt -> one memset covers both
    size_t zero_bytes = off;                          // cnt + stgcnt (incl. pads)
    float* dinv1 = (float*)carve((size_t)NN * 4);
    float* dinv2 = (float*)carve((size_t)NN * 4);
    int* rp1 = (int*)carve((size_t)(NN + 1) * 4);
    int* rp2 = (int*)carve((size_t)(NN + 1) * 4);
    int2* pk1 = (int2*)carve((size_t)NE * 8);
    int2* pk2 = (int2*)carve((size_t)NE * 8);
    int2* stg = (int2*)carve((size_t)2 * NPART * STG_CAP * 8);  // 13.9 MB
    int* bsum = (int*)carve((size_t)SCAN_BLKS * 4);
    int* boff = (int*)carve((size_t)SCAN_BLKS * 4);
    float* hpre = (float*)carve((size_t)NN * DF * 4);
    float* hbuf = (float*)carve((size_t)NN * DF * 4);
    int* exloc = (int*)hpre;  // alias: exloc dead before first gemm writes hpre

    float* outz  = (float*)d_out;                     // z  = layer-2 output
    float* outxr = (float*)d_out + (size_t)NN * DF;   // xr = layer-4 output

    const int gGemm = (NN + GEMM_ROWS - 1) / GEMM_ROWS;
    const int gAgg = (NN + 3) / 4;
    const int gPlace = 2 * NPART * CHUNKS;            // 256 blocks

    // ---- graph preprocessing: bin -> hist -> scan -> place(sorted) ----
    hipMemsetAsync(cnt, 0, zero_bytes, stream);
    bin_kernel<<<BIN_BLOCKS, 256, 0, stream>>>(src1, dst1, src2, dst2, stg, stgcnt);
    histp_kernel<<<PP_BLOCKS, 256, 0, stream>>>(stg, stgcnt, cnt);
    scanA_kernel<<<SCAN_BLKS, 1024, 0, stream>>>(cnt, exloc, bsum);
    scanB_kernel<<<1, 128, 0, stream>>>(bsum, boff, rp1, rp2);
    scanC_kernel<<<SCAN_BLKS, 1024, 0, stream>>>(cnt, exloc, boff, rp1, dinv1, rp2, dinv2);
    place_sorted_kernel<<<gPlace, 256, 0, stream>>>(stg, stgcnt, rp1, rp2, dinv1, dinv2, pk1, pk2);

    // ---- layer 1: ELU(gcn(x, ei1, W1, b1)) -> hbuf ----
    gemm128_kernel<<<gGemm, 256, 0, stream>>>(x, W1, hpre, NN);
    agg_kernel<<<gAgg, 256, 0, stream>>>(hpre, rp1, pk1, dinv1, b1, hbuf, NN, 0);
    // ---- layer 2: z = ELU(gcn(hbuf, ei2, W2, b2)) -> d_out ----
    gemm128_kernel<<<gGemm, 256, 0, stream>>>(hbuf, W2, hpre, NN);
    agg_kernel<<<gAgg, 256, 0, stream>>>(hpre, rp2, pk2, dinv2, b2, outz, NN, 0);
    // ---- layer 3: ELU(gcn(z, ei1, W3, b3)) -> hbuf ----
    gemm128_kernel<<<gGemm, 256, 0, stream>>>(outz, W3, hpre, NN);
    agg_kernel<<<gAgg, 256, 0, stream>>>(hpre, rp1, pk1, dinv1, b3, hbuf, NN, 0);
    // ---- layer 4: xr = ReLU(gcn(hbuf, ei2, W4, b4)) -> d_out[N*DF:] ----
    gemm128_kernel<<<gGemm, 256, 0, stream>>>(hbuf, W4, hpre, NN);
    agg_kernel<<<gAgg, 256, 0, stream>>>(hpre, rp2, pk2, dinv2, b4, outxr, NN, 1);
}

// Round 7
// 566.543 us; speedup vs baseline: 1.2193x; 1.2193x over previous
//
#include <hip/hip_runtime.h>
#include <math.h>

#define NN 50000
#define NE 800000
#define DF 128
#define GEMM_ROWS 64
#define NPART 8
#define PART_SZ (NN / NPART)        // 6250, exact
#define STG_CAP 108544              // part segment: 100000 expected + slack
#define BIN_BLOCKS 512
#define BUCK_CAP 512
#define CHUNKS 16                   // chunks per part
#define CH_W 391                    // ceil(PART_SZ / CHUNKS); last chunk = 385
#define SUB_CAP 7680                // chunk mean 6256 edges, +18 sigma
#define SB_CAP 448                  // subbin bucket capacity
#define SB_TH 192                   // subbin flush threshold (191 leftover + 256 <= 448)
#define SUBBIN_BLOCKS 512           // 16 segments x 32 slices

// ---------------- phase 1: bin edges by dst-part into staging (r5-proven) ----------------
__global__ __launch_bounds__(256) void bin_kernel(const int* __restrict__ src1, const int* __restrict__ dst1,
                                                  const int* __restrict__ src2, const int* __restrict__ dst2,
                                                  int2* __restrict__ stg, int* __restrict__ stgcnt) {
    __shared__ int2 buck[NPART][BUCK_CAP];   // 32 KB
    __shared__ int bcnt[NPART];
    __shared__ int wbase[4][NPART];
    __shared__ int gbase[NPART];
    const int t = threadIdx.x, lane = t & 63, w = t >> 6;
    const int g = (blockIdx.x >= BIN_BLOCKS / 2) ? 1 : 0;
    const int bid = blockIdx.x - g * (BIN_BLOCKS / 2);
    const int nb = BIN_BLOCKS / 2;
    const int* __restrict__ srcv = g ? src2 : src1;
    const int* __restrict__ dstv = g ? dst2 : dst1;
    int2* __restrict__ stg_g = stg + (size_t)g * NPART * STG_CAP;
    int* __restrict__ cnt_g = stgcnt + g * NPART;
    if (t < NPART) bcnt[t] = 0;
    __syncthreads();
    for (int base = bid * 256; base < NE; base += nb * 256) {
        const int e = base + t;
        const bool v = (e < NE);
        int d = 0, s = 0, p = -1;
        if (v) { d = dstv[e]; s = srcv[e]; p = d / PART_SZ; }
        int rank = 0;
        const unsigned long long lt = (1ull << lane) - 1ull;
        int wc[NPART];
        #pragma unroll
        for (int q = 0; q < NPART; q++) {
            unsigned long long m = __ballot(p == q);
            wc[q] = (int)__popcll(m);
            if (p == q) rank = (int)__popcll(m & lt);
        }
        if (lane < NPART) wbase[w][lane] = wc[lane];
        __syncthreads();
        if (t < NPART) {
            int b = bcnt[t];
            int c0 = wbase[0][t], c1 = wbase[1][t], c2 = wbase[2][t], c3 = wbase[3][t];
            wbase[0][t] = b; wbase[1][t] = b + c0;
            wbase[2][t] = b + c0 + c1; wbase[3][t] = b + c0 + c1 + c2;
            bcnt[t] = b + c0 + c1 + c2 + c3;
        }
        __syncthreads();
        if (v) buck[p][wbase[w][p] + rank] = make_int2(s, d);
        __syncthreads();
        const bool last = (base + nb * 256) >= NE;
        if (t < NPART) {
            int c = bcnt[t];
            gbase[t] = (c >= 256 || (last && c > 0)) ? atomicAdd(&cnt_g[t], c) : -1;
        }
        __syncthreads();
        #pragma unroll
        for (int q = 0; q < NPART; q++) {
            int gb = gbase[q];
            if (gb >= 0) {
                int c = bcnt[q];
                for (int i = t; i < c; i += 256)
                    stg_g[(size_t)q * STG_CAP + gb + i] = buck[q][i];
            }
        }
        __syncthreads();
        if (t < NPART && gbase[t] >= 0) bcnt[t] = 0;
    }
}

// ---------------- phase 2: sub-bin part segments into 16 chunk sub-segments ----------------
__global__ __launch_bounds__(256) void subbin_kernel(const int2* __restrict__ stg, const int* __restrict__ stgcnt,
                                                     int2* __restrict__ stg2, int* __restrict__ subcnt) {
    __shared__ int2 buck[CHUNKS][SB_CAP];   // 56 KB
    __shared__ int bcnt[CHUNKS];
    __shared__ int wbase[4][CHUNKS];
    __shared__ int gbase[CHUNKS];
    const int t = threadIdx.x, lane = t & 63, w = t >> 6;
    const int p = blockIdx.x & 7;                    // XCD pin: part p -> XCD p
    const int g = (blockIdx.x >> 3) & 1;
    const int slice = blockIdx.x >> 4;               // 0..31
    const int nsl = SUBBIN_BLOCKS / 16;              // 32
    const int m = stgcnt[g * NPART + p];
    const int2* __restrict__ seg = stg + ((size_t)g * NPART + p) * STG_CAP;
    const int segi0 = g * 128 + p * CHUNKS;
    int* __restrict__ cnt_c = subcnt + segi0;
    int2* __restrict__ out = stg2 + (size_t)segi0 * SUB_CAP;
    const int plo = p * PART_SZ;
    if (t < CHUNKS) bcnt[t] = 0;
    __syncthreads();
    for (int base = slice * 256; base < m; base += nsl * 256) {  // m block-uniform
        const int e = base + t;
        const bool v = (e < m);
        int2 ed = make_int2(0, 0);
        int q = -1;
        if (v) { ed = seg[e]; q = (ed.y - plo) / CH_W; }
        int rank = 0;
        const unsigned long long lt = (1ull << lane) - 1ull;
        int wc[CHUNKS];
        #pragma unroll
        for (int qq = 0; qq < CHUNKS; qq++) {
            unsigned long long mm = __ballot(q == qq);
            wc[qq] = (int)__popcll(mm);
            if (q == qq) rank = (int)__popcll(mm & lt);
        }
        if (lane < CHUNKS) wbase[w][lane] = wc[lane];
        __syncthreads();
        if (t < CHUNKS) {
            int b = bcnt[t];
            int c0 = wbase[0][t], c1 = wbase[1][t], c2 = wbase[2][t], c3 = wbase[3][t];
            wbase[0][t] = b; wbase[1][t] = b + c0;
            wbase[2][t] = b + c0 + c1; wbase[3][t] = b + c0 + c1 + c2;
            bcnt[t] = b + c0 + c1 + c2 + c3;               // <= 191 + 256 <= 447
        }
        __syncthreads();
        if (v) buck[q][wbase[w][q] + rank] = ed;
        __syncthreads();
        const bool last = (base + nsl * 256) >= m;
        if (t < CHUNKS) {
            int c = bcnt[t];
            gbase[t] = (c >= SB_TH || (last && c > 0)) ? atomicAdd(&cnt_c[t], c) : -1;
        }
        __syncthreads();
        #pragma unroll
        for (int qq = 0; qq < CHUNKS; qq++) {
            int gb = gbase[qq];
            if (gb >= 0) {
                int c = bcnt[qq];
                for (int i = t; i < c; i += 256)
                    if (gb + i < SUB_CAP)
                        out[(size_t)qq * SUB_CAP + gb + i] = buck[qq][i];
            }
        }
        __syncthreads();
        if (t < CHUNKS && gbase[t] >= 0) bcnt[t] = 0;
    }
}

// ---------------- phase 3: scan the 256 chunk counts -> chunk bases (node order) ----------------
__global__ __launch_bounds__(256) void chunkscan_kernel(const int* __restrict__ subcnt, int* __restrict__ cbase,
                                                        int* __restrict__ rp1, int* __restrict__ rp2) {
    __shared__ int wtot[4];
    const int t = threadIdx.x, lane = t & 63, w = t >> 6;  // w0,w1: graph0; w2,w3: graph1
    int v = subcnt[t];
    int x = v;
    #pragma unroll
    for (int off = 1; off < 64; off <<= 1) { int y = __shfl_up(x, off); if (lane >= off) x += y; }
    if (lane == 63) wtot[w] = x;
    __syncthreads();
    int add = (w == 1) ? wtot[0] : ((w == 3) ? wtot[2] : 0);
    cbase[t] = x - v + add;
    if (t == 0) { rp1[NN] = NE; rp2[NN] = NE; }
}

// ---------------- phase 4: per-chunk degree hist + LDS scan -> rp slice + dinv slice ----------------
// Replaces global-atomic histogram + the two 100K-element scan kernels.
__global__ __launch_bounds__(256) void histrp_kernel(const int2* __restrict__ stg2, const int* __restrict__ subcnt,
                                                     const int* __restrict__ cbase,
                                                     int* __restrict__ rp1, float* __restrict__ dinv1,
                                                     int* __restrict__ rp2, float* __restrict__ dinv2) {
    __shared__ int deg[512];
    const int t = threadIdx.x;
    const int p = blockIdx.x & 7, c = (blockIdx.x >> 3) & 15, g = blockIdx.x >> 7;
    const int segi = g * 128 + p * CHUNKS + c;
    int m = subcnt[segi];
    if (m > SUB_CAP) m = SUB_CAP;
    const int2* __restrict__ seg = stg2 + (size_t)segi * SUB_CAP;
    int* __restrict__ rp = g ? rp2 : rp1;
    float* __restrict__ dinv = g ? dinv2 : dinv1;
    const int lo = p * PART_SZ + c * CH_W;
    int hi = lo + CH_W;
    const int pend = (p + 1) * PART_SZ;
    if (hi > pend) hi = pend;
    const int nw = hi - lo;
    deg[t] = 0; deg[t + 256] = 0;
    __syncthreads();
    for (int i = t; i < m; i += 256) atomicAdd(&deg[seg[i].y - lo], 1);
    __syncthreads();
    // dinv from raw degree (before in-place scan destroys it)
    if (t < nw) dinv[lo + t] = rsqrtf((float)deg[t] + 1.0f);
    if (t + 256 < nw) dinv[lo + t + 256] = rsqrtf((float)deg[t + 256] + 1.0f);
    // Hillis-Steele inclusive scan over 512 slots (read; barrier; write; barrier)
    #pragma unroll
    for (int off = 1; off < 512; off <<= 1) {
        int v0 = (t >= off) ? deg[t - off] : 0;
        int v1 = (t + 256 >= off) ? deg[t + 256 - off] : 0;
        __syncthreads();
        deg[t] += v0; deg[t + 256] += v1;
        __syncthreads();
    }
    const int base = cbase[segi];
    if (t < nw) rp[lo + t] = base + (t ? deg[t - 1] : 0);
    if (t + 256 < nw) rp[lo + t + 256] = base + deg[t + 256 - 1];
}

// ---------------- phase 5: LDS-sorted placement from OWN sub-segment only ----------------
__global__ __launch_bounds__(256) void place_kernel(const int2* __restrict__ stg2, const int* __restrict__ subcnt,
                                                    const int* __restrict__ rp1, const int* __restrict__ rp2,
                                                    const float* __restrict__ dinv1, const float* __restrict__ dinv2,
                                                    int2* __restrict__ pk1, int2* __restrict__ pk2) {
    __shared__ int2 sorted[SUB_CAP];    // 60 KB
    __shared__ int fill[CH_W];
    __shared__ int rps[CH_W + 1];
    const int t = threadIdx.x;
    const int p = blockIdx.x & 7, c = (blockIdx.x >> 3) & 15, g = blockIdx.x >> 7;
    const int segi = g * 128 + p * CHUNKS + c;
    int m = subcnt[segi];
    if (m > SUB_CAP) m = SUB_CAP;
    const int2* __restrict__ seg = stg2 + (size_t)segi * SUB_CAP;
    const int* __restrict__ rp = g ? rp2 : rp1;
    const float* __restrict__ dinv = g ? dinv2 : dinv1;
    int2* __restrict__ pk = g ? pk2 : pk1;
    const int lo = p * PART_SZ + c * CH_W;
    int hi = lo + CH_W;
    const int pend = (p + 1) * PART_SZ;
    if (hi > pend) hi = pend;
    const int nw = hi - lo;
    for (int i = t; i < nw; i += 256) { fill[i] = 0; rps[i] = rp[lo + i]; }
    if (t == 0) rps[nw] = rp[hi];
    __syncthreads();
    const int segbase = rps[0];
    const int total = rps[nw] - segbase;
    for (int i = t; i < m; i += 256) {
        int2 e = seg[i];
        int dl = e.y - lo;
        int lp = rps[dl] - segbase + atomicAdd(&fill[dl], 1);
        if (lp < SUB_CAP)
            sorted[lp] = make_int2(e.x, __float_as_int(dinv[e.x]));
    }
    __syncthreads();
    for (int i = t; i < total; i += 256)     // coalesced 8B stores
        pk[segbase + i] = sorted[i];
}

// ---------------- H = X @ W ----------------
__global__ __launch_bounds__(256) void gemm128_kernel(const float* __restrict__ X, const float* __restrict__ W,
                                                      float* __restrict__ H, int n) {
    __shared__ __align__(16) float Xs[GEMM_ROWS * DF];  // 32 KB
    const int t = threadIdx.x;
    const int row_base = blockIdx.x * GEMM_ROWS;
    {
        const float4* X4 = (const float4*)(X + (size_t)row_base * DF);
        float4* Xs4 = (float4*)Xs;
        #pragma unroll
        for (int it = 0; it < (GEMM_ROWS * DF / 4) / 256; it++) {
            int idx = t + 256 * it;
            int r = idx >> 5;
            float4 v = make_float4(0.f, 0.f, 0.f, 0.f);
            if (row_base + r < n) v = X4[idx];
            Xs4[idx] = v;
        }
    }
    __syncthreads();
    const int cg = t & 31;
    const int rg = t >> 5;
    const int c0 = cg * 4;
    const int lr0 = rg * 8;
    float4 acc[8];
    #pragma unroll
    for (int r = 0; r < 8; r++) acc[r] = make_float4(0.f, 0.f, 0.f, 0.f);
    #pragma unroll 4
    for (int k0 = 0; k0 < DF; k0 += 4) {
        float4 wv0 = *(const float4*)(W + (size_t)(k0 + 0) * DF + c0);
        float4 wv1 = *(const float4*)(W + (size_t)(k0 + 1) * DF + c0);
        float4 wv2 = *(const float4*)(W + (size_t)(k0 + 2) * DF + c0);
        float4 wv3 = *(const float4*)(W + (size_t)(k0 + 3) * DF + c0);
        #pragma unroll
        for (int r = 0; r < 8; r++) {
            float4 xv = *(const float4*)(Xs + (lr0 + r) * DF + k0);
            acc[r].x = fmaf(xv.x, wv0.x, acc[r].x); acc[r].y = fmaf(xv.x, wv0.y, acc[r].y);
            acc[r].z = fmaf(xv.x, wv0.z, acc[r].z); acc[r].w = fmaf(xv.x, wv0.w, acc[r].w);
            acc[r].x = fmaf(xv.y, wv1.x, acc[r].x); acc[r].y = fmaf(xv.y, wv1.y, acc[r].y);
            acc[r].z = fmaf(xv.y, wv1.z, acc[r].z); acc[r].w = fmaf(xv.y, wv1.w, acc[r].w);
            acc[r].x = fmaf(xv.z, wv2.x, acc[r].x); acc[r].y = fmaf(xv.z, wv2.y, acc[r].y);
            acc[r].z = fmaf(xv.z, wv2.z, acc[r].z); acc[r].w = fmaf(xv.z, wv2.w, acc[r].w);
            acc[r].x = fmaf(xv.w, wv3.x, acc[r].x); acc[r].y = fmaf(xv.w, wv3.y, acc[r].y);
            acc[r].z = fmaf(xv.w, wv3.z, acc[r].z); acc[r].w = fmaf(xv.w, wv3.w, acc[r].w);
        }
    }
    #pragma unroll
    for (int r = 0; r < 8; r++) {
        int row = row_base + lr0 + r;
        if (row < n) *(float4*)(H + (size_t)row * DF + c0) = acc[r];
    }
}

// ---------------- aggregation: one wave per dst node ----------------
__global__ __launch_bounds__(256) void agg_kernel(const float* __restrict__ H, const int* __restrict__ rp,
                                                  const int2* __restrict__ pk,
                                                  const float* __restrict__ dinv, const float* __restrict__ bias,
                                                  float* __restrict__ out, int n, int act) {
    const int lane = threadIdx.x & 63;
    const int sub = lane & 31;
    const int half = lane >> 5;
    const int i = blockIdx.x * 4 + (threadIdx.x >> 6);
    if (i >= n) return;
    const int start = rp[i];
    const int end = rp[i + 1];
    float ax = 0.f, ay = 0.f, az = 0.f, aw = 0.f;
    const float* __restrict__ Hc = H + 4 * sub;
    for (int base = start; base < end; base += 64) {
        int cnt = end - base;
        if (cnt > 64) cnt = 64;
        int msrc = 0;
        float mdv = 0.f;
        if (lane < cnt) {
            int2 pv = pk[base + lane];
            msrc = pv.x;
            mdv = __int_as_float(pv.y);
        }
        for (int j = 0; j < cnt; j += 8) {
            int e0 = j + half;
            int s0 = __shfl(msrc, e0),     s1 = __shfl(msrc, e0 + 2);
            int s2 = __shfl(msrc, e0 + 4), s3 = __shfl(msrc, e0 + 6);
            float d0 = __shfl(mdv, e0),     d1 = __shfl(mdv, e0 + 2);
            float d2 = __shfl(mdv, e0 + 4), d3 = __shfl(mdv, e0 + 6);
            float4 h0 = *(const float4*)(Hc + (size_t)s0 * DF);
            float4 h1 = *(const float4*)(Hc + (size_t)s1 * DF);
            float4 h2 = *(const float4*)(Hc + (size_t)s2 * DF);
            float4 h3 = *(const float4*)(Hc + (size_t)s3 * DF);
            ax = fmaf(d0, h0.x, ax); ay = fmaf(d0, h0.y, ay); az = fmaf(d0, h0.z, az); aw = fmaf(d0, h0.w, aw);
            ax = fmaf(d1, h1.x, ax); ay = fmaf(d1, h1.y, ay); az = fmaf(d1, h1.z, az); aw = fmaf(d1, h1.w, aw);
            ax = fmaf(d2, h2.x, ax); ay = fmaf(d2, h2.y, ay); az = fmaf(d2, h2.z, az); aw = fmaf(d2, h2.w, aw);
            ax = fmaf(d3, h3.x, ax); ay = fmaf(d3, h3.y, ay); az = fmaf(d3, h3.z, az); aw = fmaf(d3, h3.w, aw);
        }
    }
    ax += __shfl_down(ax, 32); ay += __shfl_down(ay, 32);
    az += __shfl_down(az, 32); aw += __shfl_down(aw, 32);
    if (half == 0) {
        float di = dinv[i];
        float dii = di * di;
        float4 hv = *(const float4*)(H + (size_t)i * DF + 4 * sub);
        float4 bv = *(const float4*)(bias + 4 * sub);
        float ox = fmaf(di, ax, fmaf(dii, hv.x, bv.x));
        float oy = fmaf(di, ay, fmaf(dii, hv.y, bv.y));
        float oz = fmaf(di, az, fmaf(dii, hv.z, bv.z));
        float ow = fmaf(di, aw, fmaf(dii, hv.w, bv.w));
        if (act == 0) {  // ELU
            ox = ox > 0.f ? ox : expm1f(ox);
            oy = oy > 0.f ? oy : expm1f(oy);
            oz = oz > 0.f ? oz : expm1f(oz);
            ow = ow > 0.f ? ow : expm1f(ow);
        } else {  // ReLU
            ox = fmaxf(ox, 0.f); oy = fmaxf(oy, 0.f);
            oz = fmaxf(oz, 0.f); ow = fmaxf(ow, 0.f);
        }
        float4 ov; ov.x = ox; ov.y = oy; ov.z = oz; ov.w = ow;
        *(float4*)(out + (size_t)i * DF + 4 * sub) = ov;
    }
}

extern "C" void kernel_launch(void* const* d_in, const int* in_sizes, int n_in,
                              void* d_out, int out_size, void* d_ws, size_t ws_size,
                              hipStream_t stream) {
    const float* x  = (const float*)d_in[0];
    const float* W1 = (const float*)d_in[1];
    const float* b1 = (const float*)d_in[2];
    const float* W2 = (const float*)d_in[3];
    const float* b2 = (const float*)d_in[4];
    const float* W3 = (const float*)d_in[5];
    const float* b3 = (const float*)d_in[6];
    const float* W4 = (const float*)d_in[7];
    const float* b4 = (const float*)d_in[8];
    const int* ei1 = (const int*)d_in[9];
    const int* ei2 = (const int*)d_in[10];
    const int *src1 = ei1, *dst1 = ei1 + NE;
    const int *src2 = ei2, *dst2 = ei2 + NE;

    // ---- workspace carve-out (512B aligned), ~79 MB ----
    char* ws = (char*)d_ws;
    size_t off = 0;
    auto carve = [&](size_t bytes) -> void* {
        void* p = (void*)(ws + off);
        off += (bytes + 511) & ~(size_t)511;
        return p;
    };
    int* stgcnt = (int*)carve((size_t)16 * 4);            // bin counters
    int* subcnt = (int*)carve((size_t)256 * 4);           // subbin counters (adjacent -> one memset)
    size_t zero_bytes = off;
    int* cbase = (int*)carve((size_t)256 * 4);
    float* dinv1 = (float*)carve((size_t)NN * 4);
    float* dinv2 = (float*)carve((size_t)NN * 4);
    int* rp1 = (int*)carve((size_t)(NN + 1) * 4);
    int* rp2 = (int*)carve((size_t)(NN + 1) * 4);
    int2* pk1 = (int2*)carve((size_t)NE * 8);
    int2* pk2 = (int2*)carve((size_t)NE * 8);
    int2* stg = (int2*)carve((size_t)2 * NPART * STG_CAP * 8);   // 13.9 MB
    float* hpre = (float*)carve((size_t)NN * DF * 4);     // 25.6 MB
    float* hbuf = (float*)carve((size_t)NN * DF * 4);
    int2* stg2 = (int2*)hpre;  // alias: stg2 (15.7 MB) dead before first gemm writes hpre

    float* outz  = (float*)d_out;
    float* outxr = (float*)d_out + (size_t)NN * DF;

    const int gGemm = (NN + GEMM_ROWS - 1) / GEMM_ROWS;
    const int gAgg = (NN + 3) / 4;
    const int gChunk = 2 * NPART * CHUNKS;                // 256 blocks

    // ---- preprocessing: bin -> subbin -> chunkscan -> histrp -> place ----
    hipMemsetAsync(stgcnt, 0, zero_bytes, stream);
    bin_kernel<<<BIN_BLOCKS, 256, 0, stream>>>(src1, dst1, src2, dst2, stg, stgcnt);
    subbin_kernel<<<SUBBIN_BLOCKS, 256, 0, stream>>>(stg, stgcnt, stg2, subcnt);
    chunkscan_kernel<<<1, 256, 0, stream>>>(subcnt, cbase, rp1, rp2);
    histrp_kernel<<<gChunk, 256, 0, stream>>>(stg2, subcnt, cbase, rp1, dinv1, rp2, dinv2);
    place_kernel<<<gChunk, 256, 0, stream>>>(stg2, subcnt, rp1, rp2, dinv1, dinv2, pk1, pk2);

    // ---- layer 1: ELU(gcn(x, ei1, W1, b1)) -> hbuf ----
    gemm128_kernel<<<gGemm, 256, 0, stream>>>(x, W1, hpre, NN);
    agg_kernel<<<gAgg, 256, 0, stream>>>(hpre, rp1, pk1, dinv1, b1, hbuf, NN, 0);
    // ---- layer 2: z = ELU(gcn(hbuf, ei2, W2, b2)) -> d_out ----
    gemm128_kernel<<<gGemm, 256, 0, stream>>>(hbuf, W2, hpre, NN);
    agg_kernel<<<gAgg, 256, 0, stream>>>(hpre, rp2, pk2, dinv2, b2, outz, NN, 0);
    // ---- layer 3: ELU(gcn(z, ei1, W3, b3)) -> hbuf ----
    gemm128_kernel<<<gGemm, 256, 0, stream>>>(outz, W3, hpre, NN);
    agg_kernel<<<gAgg, 256, 0, stream>>>(hpre, rp1, pk1, dinv1, b3, hbuf, NN, 0);
    // ---- layer 4: xr = ReLU(gcn(hbuf, ei2, W4, b4)) -> d_out[N*DF:] ----
    gemm128_kernel<<<gGemm, 256, 0, stream>>>(hbuf, W4, hpre, NN);
    agg_kernel<<<gAgg, 256, 0, stream>>>(hpre, rp2, pk2, dinv2, b4, outxr, NN, 1);
}

// Round 8
// 470.566 us; speedup vs baseline: 1.4680x; 1.2040x over previous
//
#include <hip/hip_runtime.h>
#include <math.h>

#define NN 50000
#define NE 800000
#define DF 128
#define GEMM_ROWS 64
#define NPART 8
#define PART_SZ (NN / NPART)        // 6250, exact
#define STG_CAP 108544              // part segment: 100000 expected + slack
#define BIN_BLOCKS 512
#define BUCK_CAP 512
#define CHUNKS 16                   // chunks per part
#define CH_W 391                    // ceil(PART_SZ / CHUNKS); last chunk = 385
#define SUB_CAP 7680                // chunk mean 6256 edges, +18 sigma
#define SB_CAP 448                  // subbin bucket capacity
#define SB_TH 192                   // subbin flush threshold
#define SUBBIN_BLOCKS 512           // 16 segments x 32 slices

__device__ __forceinline__ unsigned short f2bf(float f) {  // round-to-nearest-even
    unsigned u = __float_as_uint(f);
    return (unsigned short)((u + 0x7FFF + ((u >> 16) & 1)) >> 16);
}
#define BF2F(u) __uint_as_float(((unsigned)(u)) << 16)

// ---------------- phase 1: bin edges by dst-part into staging (r5-proven) ----------------
__global__ __launch_bounds__(256) void bin_kernel(const int* __restrict__ src1, const int* __restrict__ dst1,
                                                  const int* __restrict__ src2, const int* __restrict__ dst2,
                                                  int2* __restrict__ stg, int* __restrict__ stgcnt) {
    __shared__ int2 buck[NPART][BUCK_CAP];   // 32 KB
    __shared__ int bcnt[NPART];
    __shared__ int wbase[4][NPART];
    __shared__ int gbase[NPART];
    const int t = threadIdx.x, lane = t & 63, w = t >> 6;
    const int g = (blockIdx.x >= BIN_BLOCKS / 2) ? 1 : 0;
    const int bid = blockIdx.x - g * (BIN_BLOCKS / 2);
    const int nb = BIN_BLOCKS / 2;
    const int* __restrict__ srcv = g ? src2 : src1;
    const int* __restrict__ dstv = g ? dst2 : dst1;
    int2* __restrict__ stg_g = stg + (size_t)g * NPART * STG_CAP;
    int* __restrict__ cnt_g = stgcnt + g * NPART;
    if (t < NPART) bcnt[t] = 0;
    __syncthreads();
    for (int base = bid * 256; base < NE; base += nb * 256) {
        const int e = base + t;
        const bool v = (e < NE);
        int d = 0, s = 0, p = -1;
        if (v) { d = dstv[e]; s = srcv[e]; p = d / PART_SZ; }
        int rank = 0;
        const unsigned long long lt = (1ull << lane) - 1ull;
        int wc[NPART];
        #pragma unroll
        for (int q = 0; q < NPART; q++) {
            unsigned long long m = __ballot(p == q);
            wc[q] = (int)__popcll(m);
            if (p == q) rank = (int)__popcll(m & lt);
        }
        if (lane < NPART) wbase[w][lane] = wc[lane];
        __syncthreads();
        if (t < NPART) {
            int b = bcnt[t];
            int c0 = wbase[0][t], c1 = wbase[1][t], c2 = wbase[2][t], c3 = wbase[3][t];
            wbase[0][t] = b; wbase[1][t] = b + c0;
            wbase[2][t] = b + c0 + c1; wbase[3][t] = b + c0 + c1 + c2;
            bcnt[t] = b + c0 + c1 + c2 + c3;
        }
        __syncthreads();
        if (v) buck[p][wbase[w][p] + rank] = make_int2(s, d);
        __syncthreads();
        const bool last = (base + nb * 256) >= NE;
        if (t < NPART) {
            int c = bcnt[t];
            gbase[t] = (c >= 256 || (last && c > 0)) ? atomicAdd(&cnt_g[t], c) : -1;
        }
        __syncthreads();
        #pragma unroll
        for (int q = 0; q < NPART; q++) {
            int gb = gbase[q];
            if (gb >= 0) {
                int c = bcnt[q];
                for (int i = t; i < c; i += 256)
                    stg_g[(size_t)q * STG_CAP + gb + i] = buck[q][i];
            }
        }
        __syncthreads();
        if (t < NPART && gbase[t] >= 0) bcnt[t] = 0;
    }
}

// ---------------- phase 2: sub-bin part segments into 16 chunk sub-segments ----------------
__global__ __launch_bounds__(256) void subbin_kernel(const int2* __restrict__ stg, const int* __restrict__ stgcnt,
                                                     int2* __restrict__ stg2, int* __restrict__ subcnt) {
    __shared__ int2 buck[CHUNKS][SB_CAP];   // 56 KB
    __shared__ int bcnt[CHUNKS];
    __shared__ int wbase[4][CHUNKS];
    __shared__ int gbase[CHUNKS];
    const int t = threadIdx.x, lane = t & 63, w = t >> 6;
    const int p = blockIdx.x & 7;
    const int g = (blockIdx.x >> 3) & 1;
    const int slice = blockIdx.x >> 4;               // 0..31
    const int nsl = SUBBIN_BLOCKS / 16;              // 32
    const int m = stgcnt[g * NPART + p];
    const int2* __restrict__ seg = stg + ((size_t)g * NPART + p) * STG_CAP;
    const int segi0 = g * 128 + p * CHUNKS;
    int* __restrict__ cnt_c = subcnt + segi0;
    int2* __restrict__ out = stg2 + (size_t)segi0 * SUB_CAP;
    const int plo = p * PART_SZ;
    if (t < CHUNKS) bcnt[t] = 0;
    __syncthreads();
    for (int base = slice * 256; base < m; base += nsl * 256) {
        const int e = base + t;
        const bool v = (e < m);
        int2 ed = make_int2(0, 0);
        int q = -1;
        if (v) { ed = seg[e]; q = (ed.y - plo) / CH_W; }
        int rank = 0;
        const unsigned long long lt = (1ull << lane) - 1ull;
        int wc[CHUNKS];
        #pragma unroll
        for (int qq = 0; qq < CHUNKS; qq++) {
            unsigned long long mm = __ballot(q == qq);
            wc[qq] = (int)__popcll(mm);
            if (q == qq) rank = (int)__popcll(mm & lt);
        }
        if (lane < CHUNKS) wbase[w][lane] = wc[lane];
        __syncthreads();
        if (t < CHUNKS) {
            int b = bcnt[t];
            int c0 = wbase[0][t], c1 = wbase[1][t], c2 = wbase[2][t], c3 = wbase[3][t];
            wbase[0][t] = b; wbase[1][t] = b + c0;
            wbase[2][t] = b + c0 + c1; wbase[3][t] = b + c0 + c1 + c2;
            bcnt[t] = b + c0 + c1 + c2 + c3;
        }
        __syncthreads();
        if (v) buck[q][wbase[w][q] + rank] = ed;
        __syncthreads();
        const bool last = (base + nsl * 256) >= m;
        if (t < CHUNKS) {
            int c = bcnt[t];
            gbase[t] = (c >= SB_TH || (last && c > 0)) ? atomicAdd(&cnt_c[t], c) : -1;
        }
        __syncthreads();
        #pragma unroll
        for (int qq = 0; qq < CHUNKS; qq++) {
            int gb = gbase[qq];
            if (gb >= 0) {
                int c = bcnt[qq];
                for (int i = t; i < c; i += 256)
                    if (gb + i < SUB_CAP)
                        out[(size_t)qq * SUB_CAP + gb + i] = buck[qq][i];
            }
        }
        __syncthreads();
        if (t < CHUNKS && gbase[t] >= 0) bcnt[t] = 0;
    }
}

// ---------------- phase 3: scan the 256 chunk counts -> chunk bases ----------------
__global__ __launch_bounds__(256) void chunkscan_kernel(const int* __restrict__ subcnt, int* __restrict__ cbase,
                                                        int* __restrict__ rp1, int* __restrict__ rp2) {
    __shared__ int wtot[4];
    const int t = threadIdx.x, lane = t & 63, w = t >> 6;
    int v = subcnt[t];
    int x = v;
    #pragma unroll
    for (int off = 1; off < 64; off <<= 1) { int y = __shfl_up(x, off); if (lane >= off) x += y; }
    if (lane == 63) wtot[w] = x;
    __syncthreads();
    int add = (w == 1) ? wtot[0] : ((w == 3) ? wtot[2] : 0);
    cbase[t] = x - v + add;
    if (t == 0) { rp1[NN] = NE; rp2[NN] = NE; }
}

// ---------------- phase 4: per-chunk degree hist + LDS scan -> rp + dinv ----------------
__global__ __launch_bounds__(256) void histrp_kernel(const int2* __restrict__ stg2, const int* __restrict__ subcnt,
                                                     const int* __restrict__ cbase,
                                                     int* __restrict__ rp1, float* __restrict__ dinv1,
                                                     int* __restrict__ rp2, float* __restrict__ dinv2) {
    __shared__ int deg[512];
    const int t = threadIdx.x;
    const int p = blockIdx.x & 7, c = (blockIdx.x >> 3) & 15, g = blockIdx.x >> 7;
    const int segi = g * 128 + p * CHUNKS + c;
    int m = subcnt[segi];
    if (m > SUB_CAP) m = SUB_CAP;
    const int2* __restrict__ seg = stg2 + (size_t)segi * SUB_CAP;
    int* __restrict__ rp = g ? rp2 : rp1;
    float* __restrict__ dinv = g ? dinv2 : dinv1;
    const int lo = p * PART_SZ + c * CH_W;
    int hi = lo + CH_W;
    const int pend = (p + 1) * PART_SZ;
    if (hi > pend) hi = pend;
    const int nw = hi - lo;
    deg[t] = 0; deg[t + 256] = 0;
    __syncthreads();
    for (int i = t; i < m; i += 256) atomicAdd(&deg[seg[i].y - lo], 1);
    __syncthreads();
    if (t < nw) dinv[lo + t] = rsqrtf((float)deg[t] + 1.0f);
    if (t + 256 < nw) dinv[lo + t + 256] = rsqrtf((float)deg[t + 256] + 1.0f);
    #pragma unroll
    for (int off = 1; off < 512; off <<= 1) {
        int v0 = (t >= off) ? deg[t - off] : 0;
        int v1 = (t + 256 >= off) ? deg[t + 256 - off] : 0;
        __syncthreads();
        deg[t] += v0; deg[t + 256] += v1;
        __syncthreads();
    }
    const int base = cbase[segi];
    if (t < nw) rp[lo + t] = base + (t ? deg[t - 1] : 0);
    if (t + 256 < nw) rp[lo + t + 256] = base + deg[t + 256 - 1];
}

// ---------------- phase 5: LDS-sorted placement from OWN sub-segment ----------------
__global__ __launch_bounds__(256) void place_kernel(const int2* __restrict__ stg2, const int* __restrict__ subcnt,
                                                    const int* __restrict__ rp1, const int* __restrict__ rp2,
                                                    const float* __restrict__ dinv1, const float* __restrict__ dinv2,
                                                    int2* __restrict__ pk1, int2* __restrict__ pk2) {
    __shared__ int2 sorted[SUB_CAP];    // 60 KB
    __shared__ int fill[CH_W];
    __shared__ int rps[CH_W + 1];
    const int t = threadIdx.x;
    const int p = blockIdx.x & 7, c = (blockIdx.x >> 3) & 15, g = blockIdx.x >> 7;
    const int segi = g * 128 + p * CHUNKS + c;
    int m = subcnt[segi];
    if (m > SUB_CAP) m = SUB_CAP;
    const int2* __restrict__ seg = stg2 + (size_t)segi * SUB_CAP;
    const int* __restrict__ rp = g ? rp2 : rp1;
    const float* __restrict__ dinv = g ? dinv2 : dinv1;
    int2* __restrict__ pk = g ? pk2 : pk1;
    const int lo = p * PART_SZ + c * CH_W;
    int hi = lo + CH_W;
    const int pend = (p + 1) * PART_SZ;
    if (hi > pend) hi = pend;
    const int nw = hi - lo;
    for (int i = t; i < nw; i += 256) { fill[i] = 0; rps[i] = rp[lo + i]; }
    if (t == 0) rps[nw] = rp[hi];
    __syncthreads();
    const int segbase = rps[0];
    const int total = rps[nw] - segbase;
    for (int i = t; i < m; i += 256) {
        int2 e = seg[i];
        int dl = e.y - lo;
        int lp = rps[dl] - segbase + atomicAdd(&fill[dl], 1);
        if (lp < SUB_CAP)
            sorted[lp] = make_int2(e.x, __float_as_int(dinv[e.x]));
    }
    __syncthreads();
    for (int i = t; i < total; i += 256)
        pk[segbase + i] = sorted[i];
}

// ---------------- H = X @ W  (fp32 out + bf16 shadow copy for gathers) ----------------
__global__ __launch_bounds__(256) void gemm128_kernel(const float* __restrict__ X, const float* __restrict__ W,
                                                      float* __restrict__ H, unsigned short* __restrict__ Hb, int n) {
    __shared__ __align__(16) float Xs[GEMM_ROWS * DF];  // 32 KB
    const int t = threadIdx.x;
    const int row_base = blockIdx.x * GEMM_ROWS;
    {
        const float4* X4 = (const float4*)(X + (size_t)row_base * DF);
        float4* Xs4 = (float4*)Xs;
        #pragma unroll
        for (int it = 0; it < (GEMM_ROWS * DF / 4) / 256; it++) {
            int idx = t + 256 * it;
            int r = idx >> 5;
            float4 v = make_float4(0.f, 0.f, 0.f, 0.f);
            if (row_base + r < n) v = X4[idx];
            Xs4[idx] = v;
        }
    }
    __syncthreads();
    const int cg = t & 31;
    const int rg = t >> 5;
    const int c0 = cg * 4;
    const int lr0 = rg * 8;
    float4 acc[8];
    #pragma unroll
    for (int r = 0; r < 8; r++) acc[r] = make_float4(0.f, 0.f, 0.f, 0.f);
    #pragma unroll 4
    for (int k0 = 0; k0 < DF; k0 += 4) {
        float4 wv0 = *(const float4*)(W + (size_t)(k0 + 0) * DF + c0);
        float4 wv1 = *(const float4*)(W + (size_t)(k0 + 1) * DF + c0);
        float4 wv2 = *(const float4*)(W + (size_t)(k0 + 2) * DF + c0);
        float4 wv3 = *(const float4*)(W + (size_t)(k0 + 3) * DF + c0);
        #pragma unroll
        for (int r = 0; r < 8; r++) {
            float4 xv = *(const float4*)(Xs + (lr0 + r) * DF + k0);
            acc[r].x = fmaf(xv.x, wv0.x, acc[r].x); acc[r].y = fmaf(xv.x, wv0.y, acc[r].y);
            acc[r].z = fmaf(xv.x, wv0.z, acc[r].z); acc[r].w = fmaf(xv.x, wv0.w, acc[r].w);
            acc[r].x = fmaf(xv.y, wv1.x, acc[r].x); acc[r].y = fmaf(xv.y, wv1.y, acc[r].y);
            acc[r].z = fmaf(xv.y, wv1.z, acc[r].z); acc[r].w = fmaf(xv.y, wv1.w, acc[r].w);
            acc[r].x = fmaf(xv.z, wv2.x, acc[r].x); acc[r].y = fmaf(xv.z, wv2.y, acc[r].y);
            acc[r].z = fmaf(xv.z, wv2.z, acc[r].z); acc[r].w = fmaf(xv.z, wv2.w, acc[r].w);
            acc[r].x = fmaf(xv.w, wv3.x, acc[r].x); acc[r].y = fmaf(xv.w, wv3.y, acc[r].y);
            acc[r].z = fmaf(xv.w, wv3.z, acc[r].z); acc[r].w = fmaf(xv.w, wv3.w, acc[r].w);
        }
    }
    #pragma unroll
    for (int r = 0; r < 8; r++) {
        int row = row_base + lr0 + r;
        if (row < n) {
            *(float4*)(H + (size_t)row * DF + c0) = acc[r];
            ushort4 hb;
            hb.x = f2bf(acc[r].x); hb.y = f2bf(acc[r].y);
            hb.z = f2bf(acc[r].z); hb.w = f2bf(acc[r].w);
            *(ushort4*)(Hb + (size_t)row * DF + c0) = hb;
        }
    }
}

// ---------------- aggregation: one wave per dst node, bf16 gathers ----------------
// out[i] = act( dinv[i]*sum coef[e]*Hb[src[e]] + dinv[i]^2*H[i] + b ); self-term fp32.
__global__ __launch_bounds__(256) void agg_kernel(const float* __restrict__ H, const unsigned short* __restrict__ Hb,
                                                  const int* __restrict__ rp, const int2* __restrict__ pk,
                                                  const float* __restrict__ dinv, const float* __restrict__ bias,
                                                  float* __restrict__ out, int n, int act) {
    const int lane = threadIdx.x & 63;
    const int sub = lane & 31;
    const int half = lane >> 5;
    const int i = blockIdx.x * 4 + (threadIdx.x >> 6);
    if (i >= n) return;
    const int start = rp[i];
    const int end = rp[i + 1];
    float ax = 0.f, ay = 0.f, az = 0.f, aw = 0.f;
    const unsigned short* __restrict__ Hbc = Hb + 4 * sub;
    for (int base = start; base < end; base += 64) {
        int cnt = end - base;
        if (cnt > 64) cnt = 64;
        int msrc = 0;
        float mdv = 0.f;
        if (lane < cnt) {  // coalesced 8B batch load of packed (src, coef)
            int2 pv = pk[base + lane];
            msrc = pv.x;
            mdv = __int_as_float(pv.y);
        }
        for (int j = 0; j < cnt; j += 16) {  // 16 edges per iter; 8 x 8B gathers in flight per half
            int e0 = j + half;               // halves take even/odd edges; pads have mdv==0
            int s[8]; float d[8];
            #pragma unroll
            for (int k = 0; k < 8; k++) {
                s[k] = __shfl(msrc, e0 + 2 * k);
                d[k] = __shfl(mdv, e0 + 2 * k);
            }
            ushort4 hb[8];
            #pragma unroll
            for (int k = 0; k < 8; k++) hb[k] = *(const ushort4*)(Hbc + (size_t)s[k] * DF);
            #pragma unroll
            for (int k = 0; k < 8; k++) {
                ax = fmaf(d[k], BF2F(hb[k].x), ax);
                ay = fmaf(d[k], BF2F(hb[k].y), ay);
                az = fmaf(d[k], BF2F(hb[k].z), az);
                aw = fmaf(d[k], BF2F(hb[k].w), aw);
            }
        }
    }
    // fold halves: lanes 0-31 += lanes 32-63
    ax += __shfl_down(ax, 32); ay += __shfl_down(ay, 32);
    az += __shfl_down(az, 32); aw += __shfl_down(aw, 32);
    if (half == 0) {
        float di = dinv[i];
        float dii = di * di;
        float4 hv = *(const float4*)(H + (size_t)i * DF + 4 * sub);   // self term fp32
        float4 bv = *(const float4*)(bias + 4 * sub);
        float ox = fmaf(di, ax, fmaf(dii, hv.x, bv.x));
        float oy = fmaf(di, ay, fmaf(dii, hv.y, bv.y));
        float oz = fmaf(di, az, fmaf(dii, hv.z, bv.z));
        float ow = fmaf(di, aw, fmaf(dii, hv.w, bv.w));
        if (act == 0) {  // ELU
            ox = ox > 0.f ? ox : expm1f(ox);
            oy = oy > 0.f ? oy : expm1f(oy);
            oz = oz > 0.f ? oz : expm1f(oz);
            ow = ow > 0.f ? ow : expm1f(ow);
        } else {  // ReLU
            ox = fmaxf(ox, 0.f); oy = fmaxf(oy, 0.f);
            oz = fmaxf(oz, 0.f); ow = fmaxf(ow, 0.f);
        }
        float4 ov; ov.x = ox; ov.y = oy; ov.z = oz; ov.w = ow;
        *(float4*)(out + (size_t)i * DF + 4 * sub) = ov;
    }
}

extern "C" void kernel_launch(void* const* d_in, const int* in_sizes, int n_in,
                              void* d_out, int out_size, void* d_ws, size_t ws_size,
                              hipStream_t stream) {
    const float* x  = (const float*)d_in[0];
    const float* W1 = (const float*)d_in[1];
    const float* b1 = (const float*)d_in[2];
    const float* W2 = (const float*)d_in[3];
    const float* b2 = (const float*)d_in[4];
    const float* W3 = (const float*)d_in[5];
    const float* b3 = (const float*)d_in[6];
    const float* W4 = (const float*)d_in[7];
    const float* b4 = (const float*)d_in[8];
    const int* ei1 = (const int*)d_in[9];
    const int* ei2 = (const int*)d_in[10];
    const int *src1 = ei1, *dst1 = ei1 + NE;
    const int *src2 = ei2, *dst2 = ei2 + NE;

    // ---- workspace carve-out (512B aligned), ~79 MB ----
    char* ws = (char*)d_ws;
    size_t off = 0;
    auto carve = [&](size_t bytes) -> void* {
        void* p = (void*)(ws + off);
        off += (bytes + 511) & ~(size_t)511;
        return p;
    };
    int* stgcnt = (int*)carve((size_t)16 * 4);
    int* subcnt = (int*)carve((size_t)256 * 4);
    size_t zero_bytes = off;
    int* cbase = (int*)carve((size_t)256 * 4);
    float* dinv1 = (float*)carve((size_t)NN * 4);
    float* dinv2 = (float*)carve((size_t)NN * 4);
    int* rp1 = (int*)carve((size_t)(NN + 1) * 4);
    int* rp2 = (int*)carve((size_t)(NN + 1) * 4);
    int2* pk1 = (int2*)carve((size_t)NE * 8);
    int2* pk2 = (int2*)carve((size_t)NE * 8);
    int2* stg = (int2*)carve((size_t)2 * NPART * STG_CAP * 8);   // 13.9 MB
    float* hpre = (float*)carve((size_t)NN * DF * 4);     // 25.6 MB
    float* hbuf = (float*)carve((size_t)NN * DF * 4);
    int2* stg2 = (int2*)hpre;                 // alias: stg2 dead before first gemm writes hpre
    unsigned short* hpreb = (unsigned short*)stg;  // alias: stg dead after subbin; 12.8MB <= 13.9MB

    float* outz  = (float*)d_out;
    float* outxr = (float*)d_out + (size_t)NN * DF;

    const int gGemm = (NN + GEMM_ROWS - 1) / GEMM_ROWS;
    const int gAgg = (NN + 3) / 4;
    const int gChunk = 2 * NPART * CHUNKS;                // 256 blocks

    // ---- preprocessing: bin -> subbin -> chunkscan -> histrp -> place ----
    hipMemsetAsync(stgcnt, 0, zero_bytes, stream);
    bin_kernel<<<BIN_BLOCKS, 256, 0, stream>>>(src1, dst1, src2, dst2, stg, stgcnt);
    subbin_kernel<<<SUBBIN_BLOCKS, 256, 0, stream>>>(stg, stgcnt, stg2, subcnt);
    chunkscan_kernel<<<1, 256, 0, stream>>>(subcnt, cbase, rp1, rp2);
    histrp_kernel<<<gChunk, 256, 0, stream>>>(stg2, subcnt, cbase, rp1, dinv1, rp2, dinv2);
    place_kernel<<<gChunk, 256, 0, stream>>>(stg2, subcnt, rp1, rp2, dinv1, dinv2, pk1, pk2);

    // ---- layer 1: ELU(gcn(x, ei1, W1, b1)) -> hbuf ----
    gemm128_kernel<<<gGemm, 256, 0, stream>>>(x, W1, hpre, hpreb, NN);
    agg_kernel<<<gAgg, 256, 0, stream>>>(hpre, hpreb, rp1, pk1, dinv1, b1, hbuf, NN, 0);
    // ---- layer 2: z = ELU(gcn(hbuf, ei2, W2, b2)) -> d_out ----
    gemm128_kernel<<<gGemm, 256, 0, stream>>>(hbuf, W2, hpre, hpreb, NN);
    agg_kernel<<<gAgg, 256, 0, stream>>>(hpre, hpreb, rp2, pk2, dinv2, b2, outz, NN, 0);
    // ---- layer 3: ELU(gcn(z, ei1, W3, b3)) -> hbuf ----
    gemm128_kernel<<<gGemm, 256, 0, stream>>>(outz, W3, hpre, hpreb, NN);
    agg_kernel<<<gAgg, 256, 0, stream>>>(hpre, hpreb, rp1, pk1, dinv1, b3, hbuf, NN, 0);
    // ---- layer 4: xr = ReLU(gcn(hbuf, ei2, W4, b4)) -> d_out[N*DF:] ----
    gemm128_kernel<<<gGemm, 256, 0, stream>>>(hbuf, W4, hpre, hpreb, NN);
    agg_kernel<<<gAgg, 256, 0, stream>>>(hpre, hpreb, rp2, pk2, dinv2, b4, outxr, NN, 1);
}